// Round 2
// baseline (13665.549 us; speedup 1.0000x reference)
//
#include <hip/hip_runtime.h>
#include <hip/hip_bf16.h>
#include <cmath>

#define FPS_N 8192
#define FPS_K 4096
#define CS    256
#define FT    512          // FPS threads (8 waves)
#define PPT   16           // points per thread
#define NEGINF (-__builtin_inff())

// Minkowski-p3 "sum of |d|^3" with reference-exact f32 op order (no FMA contraction).
__device__ __forceinline__ float p3sum(float x, float y, float z,
                                       float nx, float ny, float nz) {
  float dx = fabsf(__fsub_rn(x, nx));
  float dy = fabsf(__fsub_rn(y, ny));
  float dz = fabsf(__fsub_rn(z, nz));
  float cx = __fmul_rn(__fmul_rn(dx, dx), dx);
  float cy = __fmul_rn(__fmul_rn(dy, dy), dy);
  float cz = __fmul_rn(__fmul_rn(dz, dz), dz);
  return __fadd_rn(__fadd_rn(cx, cy), cz);
}

// Squared Euclidean distance, reference-exact f32 op order.
__device__ __forceinline__ float eucl2(float x, float y, float z,
                                       float nx, float ny, float nz) {
  float dx = __fsub_rn(x, nx);
  float dy = __fsub_rn(y, ny);
  float dz = __fsub_rn(z, nz);
  return __fadd_rn(__fadd_rn(__fmul_rn(dx, dx), __fmul_rn(dy, dy)),
                   __fmul_rn(dz, dz));
}

// ---------------------------------------------------------------------------
// Spatial counting sort: Morton 8x8x8 cells over [-4,4]^3. Output order within
// a cell is nondeterministic (atomics) but the FPS result is invariant to it
// (tie-breaks & emission use original indices carried through ids_s).
// ---------------------------------------------------------------------------
__global__ __launch_bounds__(FT) void bin_kernel(const float* __restrict__ pos,
                                                 float* __restrict__ pos_s,
                                                 int* __restrict__ ids_s) {
  __shared__ int hist[512], cs[512], tmp[512];
  const int tid = threadIdx.x;
  hist[tid] = 0;
  __syncthreads();

  float qx[PPT], qy[PPT], qz[PPT];
  int cell[PPT];
  {
    const float4* p4 = (const float4*)pos + tid * 12;
#pragma unroll
    for (int g = 0; g < 4; ++g) {
      float4 a = p4[g * 3], b = p4[g * 3 + 1], c = p4[g * 3 + 2];
      qx[4*g+0]=a.x; qy[4*g+0]=a.y; qz[4*g+0]=a.z;
      qx[4*g+1]=a.w; qy[4*g+1]=b.x; qz[4*g+1]=b.y;
      qx[4*g+2]=b.z; qy[4*g+2]=b.w; qz[4*g+2]=c.x;
      qx[4*g+3]=c.y; qy[4*g+3]=c.z; qz[4*g+3]=c.w;
    }
  }
#pragma unroll
  for (int j = 0; j < PPT; ++j) {
    int ix = min(max((int)floorf(qx[j] + 4.0f), 0), 7);
    int iy = min(max((int)floorf(qy[j] + 4.0f), 0), 7);
    int iz = min(max((int)floorf(qz[j] + 4.0f), 0), 7);
    int m = 0;
#pragma unroll
    for (int b = 0; b < 3; ++b)
      m |= (((ix >> b) & 1) << (3 * b)) | (((iy >> b) & 1) << (3 * b + 1)) |
           (((iz >> b) & 1) << (3 * b + 2));
    cell[j] = m;
    atomicAdd(&hist[m], 1);
  }
  __syncthreads();
  int v = hist[tid];
  tmp[tid] = v;
  __syncthreads();
  for (int off = 1; off < 512; off <<= 1) {
    int u = (tid >= off) ? tmp[tid - off] : 0;
    __syncthreads();
    tmp[tid] += u;
    __syncthreads();
  }
  cs[tid] = tmp[tid] - v;  // exclusive prefix
  __syncthreads();
#pragma unroll
  for (int j = 0; j < PPT; ++j) {
    int slot = atomicAdd(&cs[cell[j]], 1);
    pos_s[slot * 3 + 0] = qx[j];
    pos_s[slot * 3 + 1] = qy[j];
    pos_s[slot * 3 + 2] = qz[j];
    ids_s[slot] = tid * PPT + j;
  }
}

// ---------------------------------------------------------------------------
// FPS: 512 threads, 16 spatially-clustered points/thread. Bit-exact vs
// reference: d maintained as squared min (sqrt on demand, monotone &
// correctly rounded), argmax tie-break = lowest ORIGINAL index via packed
// (value, origidx<<13|storidx) lexicographic reduce. Bbox skip is
// conservative (0.999 margin) so it never changes results.
// ---------------------------------------------------------------------------
__global__ __launch_bounds__(FT, 1) void fps_kernel(const float* __restrict__ pos,
                                                    const float* __restrict__ pos_s,
                                                    const int* __restrict__ ids_s,
                                                    float* __restrict__ pos_out) {
  __shared__ float rvv[8];
  __shared__ int   rvk[8];
  __shared__ float4 wposs;
  __shared__ unsigned char flag[FPS_N];
  __shared__ int sc[FT];

  const int tid  = threadIdx.x;
  const int lane = tid & 63;
  const int wave = tid >> 6;
  const int base = tid * PPT;

  {
    int* f4 = (int*)flag;
#pragma unroll
    for (int j = 0; j < 4; ++j) f4[tid * 4 + j] = 0;
  }

  float x[PPT], y[PPT], z[PPT], d2[PPT];
  int idp[PPT / 2];  // packed orig indices (2 x 13-bit per int)
  {
    const float4* p4 = (const float4*)pos_s + tid * 12;
#pragma unroll
    for (int g = 0; g < 4; ++g) {
      float4 a = p4[g * 3], b = p4[g * 3 + 1], c = p4[g * 3 + 2];
      x[4*g+0]=a.x; y[4*g+0]=a.y; z[4*g+0]=a.z;
      x[4*g+1]=a.w; y[4*g+1]=b.x; z[4*g+1]=b.y;
      x[4*g+2]=b.z; y[4*g+2]=b.w; z[4*g+2]=c.x;
      x[4*g+3]=c.y; y[4*g+3]=c.z; z[4*g+3]=c.w;
    }
    const int4* i4 = (const int4*)ids_s + tid * 4;
#pragma unroll
    for (int g = 0; g < 4; ++g) {
      int4 a = i4[g];
      idp[2 * g + 0] = (a.x & 0xffff) | (a.y << 16);
      idp[2 * g + 1] = (a.z & 0xffff) | (a.w << 16);
    }
  }

  const float p0x = pos[0], p0y = pos[1], p0z = pos[2];
#pragma unroll
  for (int j = 0; j < PPT; ++j) {
    d2[j] = eucl2(x[j], y[j], z[j], p0x, p0y, p0z);
    int oid = (idp[j >> 1] >> ((j & 1) * 16)) & 0xffff;
    if (oid == 0) d2[j] = NEGINF;
  }
  // thread bounding box
  float bnx = x[0], bny = y[0], bnz = z[0], bxx = x[0], bxy = y[0], bxz = z[0];
#pragma unroll
  for (int j = 1; j < PPT; ++j) {
    bnx = fminf(bnx, x[j]); bny = fminf(bny, y[j]); bnz = fminf(bnz, z[j]);
    bxx = fmaxf(bxx, x[j]); bxy = fmaxf(bxy, y[j]); bxz = fmaxf(bxz, z[j]);
  }
  if (tid == 0) flag[0] = 1;
  __syncthreads();

  float bv = NEGINF;        // cached thread-candidate value (max d)
  int   bkey = 0x7fffffff;  // (origidx<<13)|storidx of candidate
  bool  chb = true;

  for (int k = 0; k < FPS_K - 1; ++k) {
    unsigned long long cb = __ballot(chb ? 1 : 0);
    if (cb) {  // wave-uniform: refresh wave candidate
      if (chb) {
        bv = NEGINF; bkey = 0x7fffffff;
#pragma unroll
        for (int j = 0; j < PPT; ++j) {
          float dj = (d2[j] < 0.f) ? NEGINF : sqrtf(d2[j]);
          int oid = (idp[j >> 1] >> ((j & 1) * 16)) & 0xffff;
          int key = (oid << 13) | (base + j);
          if (dj > bv || (dj == bv && key < bkey)) { bv = dj; bkey = key; }
        }
        chb = false;
      }
      float v = bv; int kk = bkey;
#pragma unroll
      for (int off = 1; off < 64; off <<= 1) {
        float ov = __shfl_xor(v, off);
        int   ok = __shfl_xor(kk, off);
        if (ov > v || (ov == v && ok < kk)) { v = ov; kk = ok; }
      }
      if (lane == 0) { rvv[wave] = v; rvk[wave] = kk; }
    }
    __syncthreads();  // A: wave candidates (fresh or persisted) visible

    float4 vv0 = *(float4*)&rvv[0]; float4 vv1 = *(float4*)&rvv[4];
    int4   kk0 = *(int4*)&rvk[0];   int4   kk1 = *(int4*)&rvk[4];
    float wv = vv0.x; int wk = kk0.x;
#define CMPW(a, b) if ((a) > wv || ((a) == wv && (b) < wk)) { wv = (a); wk = (b); }
    CMPW(vv0.y, kk0.y) CMPW(vv0.z, kk0.z) CMPW(vv0.w, kk0.w)
    CMPW(vv1.x, kk1.x) CMPW(vv1.y, kk1.y) CMPW(vv1.z, kk1.z) CMPW(vv1.w, kk1.w)
#undef CMPW
    const int stor = wk & 8191;

    if ((stor >> 4) == tid) {  // owner: mark selected + publish coords
      const int jj = stor & 15;
      float sx = x[0], sy = y[0], sz = z[0];
#pragma unroll
      for (int j = 0; j < PPT; ++j)
        if (j == jj) { sx = x[j]; sy = y[j]; sz = z[j]; d2[j] = NEGINF; }
      wposs = make_float4(sx, sy, sz, 0.f);
      chb = true;
    }
    if (tid == 0) flag[wk >> 13] = 1;
    __syncthreads();  // B: winner coords visible

    const float4 wp = wposs;
    float tub = (bv < 0.f) ? NEGINF : bv * bv;  // stale-high-safe upper bound
    float cx = fminf(fmaxf(wp.x, bnx), bxx);
    float cy = fminf(fmaxf(wp.y, bny), bxy);
    float cz = fminf(fmaxf(wp.z, bnz), bxz);
    float ddx = wp.x - cx, ddy = wp.y - cy, ddz = wp.z - cz;
    float bd2 = ddx * ddx + ddy * ddy + ddz * ddz;
    if (bd2 * 0.999f < tub) {  // conservative: update only if improvement possible
#pragma unroll
      for (int j = 0; j < PPT; ++j) {
        float s = eucl2(x[j], y[j], z[j], wp.x, wp.y, wp.z);
        if (s < d2[j]) { d2[j] = s; if (j == (bkey & 15)) chb = true; }
      }
    }
  }

  // ---- emit selected points in ascending ORIGINAL index order ----
  __syncthreads();
  const int* fI = (const int*)flag;
  int w0 = fI[tid * 4 + 0], w1 = fI[tid * 4 + 1];
  int w2 = fI[tid * 4 + 2], w3 = fI[tid * 4 + 3];
  int cnt = __popc(w0) + __popc(w1) + __popc(w2) + __popc(w3);
  sc[tid] = cnt;
  __syncthreads();
  for (int off = 1; off < FT; off <<= 1) {
    int u = (tid >= off) ? sc[tid - off] : 0;
    __syncthreads();
    sc[tid] += u;
    __syncthreads();
  }
  int r = sc[tid] - cnt;
#pragma unroll
  for (int j = 0; j < PPT; ++j) {
    int w = (j < 4) ? w0 : (j < 8) ? w1 : (j < 12) ? w2 : w3;
    if ((w >> ((j & 3) * 8)) & 1) {
      int oi = tid * PPT + j;
      pos_out[r * 3 + 0] = pos[oi * 3 + 0];
      pos_out[r * 3 + 1] = pos[oi * 3 + 1];
      pos_out[r * 3 + 2] = pos[oi * 3 + 2];
      ++r;
    }
  }
}

// ---------------------------------------------------------------------------
// W^T (256x256) into scratch (start of mask region; overwritten later).
// ---------------------------------------------------------------------------
__global__ __launch_bounds__(256) void wt_kernel(const float* __restrict__ W,
                                                 float* __restrict__ WT) {
  int i = blockIdx.x * 256 + threadIdx.x;
  int c = i >> 8, cp = i & 255;
  WT[i] = W[cp * 256 + c];
}

// ---------------------------------------------------------------------------
// Fused sparse aggregation + Linear. One block per node m.
// ---------------------------------------------------------------------------
__global__ __launch_bounds__(256) void agg_linear_kernel(
    const float* __restrict__ h, const float* __restrict__ pos,
    const float* __restrict__ nodepos, const float* __restrict__ WT,
    const float* __restrict__ bias, float* __restrict__ embed, float sb) {
  const int m = blockIdx.x;
  const int tid = threadIdx.x;
  const int lane = tid & 63, wave = tid >> 6;
  const float nx = nodepos[m * 3 + 0];
  const float ny = nodepos[m * 3 + 1];
  const float nz = nodepos[m * 3 + 2];
  const float4* h4 = (const float4*)h;

  float4 acc = make_float4(0.f, 0.f, 0.f, 0.f);
  const int base0 = wave * (FPS_N / 4);
  for (int base = base0; base < base0 + (FPS_N / 4); base += 64) {
    int n = base + lane;
    float px = pos[n * 3 + 0], py = pos[n * 3 + 1], pz = pos[n * 3 + 2];
    unsigned long long mb = __ballot((p3sum(px, py, pz, nx, ny, nz) <= sb) ? 1 : 0);
    while (mb) {
      int b = __ffsll(mb) - 1;
      mb &= (mb - 1);
      float4 hv = h4[(size_t)(base + b) * 64 + lane];
      acc.x += hv.x; acc.y += hv.y; acc.z += hv.z; acc.w += hv.w;
    }
  }

  __shared__ float lacc[4][256];
  lacc[wave][lane * 4 + 0] = acc.x;
  lacc[wave][lane * 4 + 1] = acc.y;
  lacc[wave][lane * 4 + 2] = acc.z;
  lacc[wave][lane * 4 + 3] = acc.w;
  __syncthreads();
  __shared__ float aggrow[256];
  float aggv = ((lacc[0][tid] + lacc[1][tid]) + lacc[2][tid]) + lacc[3][tid];
  aggrow[tid] = aggv;
  __syncthreads();

  float o = bias[tid];
#pragma unroll 8
  for (int c = 0; c < 256; ++c)
    o = fmaf(aggrow[c], WT[c * 256 + tid], o);
  embed[(size_t)m * 256 + tid] = o;
}

// ---------------------------------------------------------------------------
// Mask output: mask[n][m] = (sum|d|^3 <= sb) ? 1.0 : 0.0   (8192 x 4096 f32)
// ---------------------------------------------------------------------------
__global__ __launch_bounds__(256) void mask_kernel(const float* __restrict__ pos,
                                                   const float* __restrict__ nodepos,
                                                   float* __restrict__ maskout,
                                                   float sb) {
  int n  = blockIdx.y;
  int m0 = (blockIdx.x * 256 + threadIdx.x) * 4;
  float x = pos[n * 3 + 0], y = pos[n * 3 + 1], z = pos[n * 3 + 2];
  const float4* np4 = (const float4*)(nodepos + (size_t)m0 * 3);
  float4 a = np4[0], bq = np4[1], cq = np4[2];
  float4 r;
  r.x = (p3sum(x, y, z, a.x,  a.y,  a.z)  <= sb) ? 1.0f : 0.0f;
  r.y = (p3sum(x, y, z, a.w,  bq.x, bq.y) <= sb) ? 1.0f : 0.0f;
  r.z = (p3sum(x, y, z, bq.z, bq.w, cq.x) <= sb) ? 1.0f : 0.0f;
  r.w = (p3sum(x, y, z, cq.y, cq.z, cq.w) <= sb) ? 1.0f : 0.0f;
  *(float4*)(maskout + (size_t)n * FPS_K + m0) = r;
}

extern "C" void kernel_launch(void* const* d_in, const int* in_sizes, int n_in,
                              void* d_out, int out_size, void* d_ws, size_t ws_size,
                              hipStream_t stream) {
  (void)in_sizes; (void)n_in; (void)out_size; (void)d_ws; (void)ws_size;
  const float* h   = (const float*)d_in[0];
  const float* pos = (const float*)d_in[1];
  const float* W   = (const float*)d_in[2];
  const float* b   = (const float*)d_in[3];

  float* out     = (float*)d_out;
  float* embed   = out;                                   // 4096*256
  float* pos_out = out + (size_t)FPS_K * CS;              // 4096*3
  float* mask    = pos_out + (size_t)FPS_K * 3;           // 8192*4096
  float* WT      = mask;                                  // scratch (overwritten)
  float* pos_s   = mask + (1 << 21);                      // sorted coords scratch
  int*   ids_s   = (int*)(pos_s + 3 * FPS_N);             // sorted->orig idx

  // Threshold model: ref mask true  <=>  cbrt_f32(s) < 0.3f
  const float  t    = 0.3f;
  const float  ulpv = nextafterf(t, 1.0f) - t;
  const double rmid = (double)t - (double)ulpv * 0.5;
  const double C    = rmid * rmid * rmid;
  float sb = (float)C;
  if (!((double)sb < C)) sb = nextafterf(sb, 0.0f);

  hipLaunchKernelGGL(bin_kernel, dim3(1), dim3(FT), 0, stream, pos, pos_s, ids_s);
  hipLaunchKernelGGL(fps_kernel, dim3(1), dim3(FT), 0, stream, pos, pos_s, ids_s, pos_out);
  hipLaunchKernelGGL(wt_kernel, dim3(256), dim3(256), 0, stream, W, WT);
  hipLaunchKernelGGL(agg_linear_kernel, dim3(FPS_K), dim3(256), 0, stream,
                     h, pos, pos_out, WT, b, embed, sb);
  hipLaunchKernelGGL(mask_kernel, dim3(4, FPS_N), dim3(256), 0, stream,
                     pos, pos_out, mask, sb);
}

// Round 3
// 7559.299 us; speedup vs baseline: 1.8078x; 1.8078x over previous
//
#include <hip/hip_runtime.h>
#include <hip/hip_bf16.h>
#include <cmath>

#define FPS_N 8192
#define FPS_K 4096
#define CS    256
#define FT    1024         // FPS threads (16 waves)
#define PPT   8            // points per thread
#define NEGINF (-__builtin_inff())

// Minkowski-p3 "sum of |d|^3" with reference-exact f32 op order (no FMA contraction).
__device__ __forceinline__ float p3sum(float x, float y, float z,
                                       float nx, float ny, float nz) {
  float dx = fabsf(__fsub_rn(x, nx));
  float dy = fabsf(__fsub_rn(y, ny));
  float dz = fabsf(__fsub_rn(z, nz));
  float cx = __fmul_rn(__fmul_rn(dx, dx), dx);
  float cy = __fmul_rn(__fmul_rn(dy, dy), dy);
  float cz = __fmul_rn(__fmul_rn(dz, dz), dz);
  return __fadd_rn(__fadd_rn(cx, cy), cz);
}

// Squared Euclidean distance, reference-exact f32 op order.
__device__ __forceinline__ float eucl2(float x, float y, float z,
                                       float nx, float ny, float nz) {
  float dx = __fsub_rn(x, nx);
  float dy = __fsub_rn(y, ny);
  float dz = __fsub_rn(z, nz);
  return __fadd_rn(__fadd_rn(__fmul_rn(dx, dx), __fmul_rn(dy, dy)),
                   __fmul_rn(dz, dz));
}

// DPP lex-max select: (v,k) with v float desc, k int asc tie-break.
template<int CTRL>
__device__ __forceinline__ void dpp_sel2(float& v, int& k) {
  int nv = __builtin_amdgcn_update_dpp(__float_as_int(v), __float_as_int(v), CTRL, 0xF, 0xF, false);
  int nk = __builtin_amdgcn_update_dpp(k, k, CTRL, 0xF, 0xF, false);
  float fv = __int_as_float(nv);
  bool t = (fv > v) || (fv == v && nk < k);
  v = t ? fv : v;
  k = t ? nk : k;
}

template<int CTRL>
__device__ __forceinline__ void dpp_sel5(float& v, int& k, float& x, float& y, float& z) {
  int nv = __builtin_amdgcn_update_dpp(__float_as_int(v), __float_as_int(v), CTRL, 0xF, 0xF, false);
  int nk = __builtin_amdgcn_update_dpp(k, k, CTRL, 0xF, 0xF, false);
  int nx = __builtin_amdgcn_update_dpp(__float_as_int(x), __float_as_int(x), CTRL, 0xF, 0xF, false);
  int ny = __builtin_amdgcn_update_dpp(__float_as_int(y), __float_as_int(y), CTRL, 0xF, 0xF, false);
  int nz = __builtin_amdgcn_update_dpp(__float_as_int(z), __float_as_int(z), CTRL, 0xF, 0xF, false);
  float fv = __int_as_float(nv);
  bool t = (fv > v) || (fv == v && nk < k);
  v = t ? fv : v;
  k = t ? nk : k;
  x = t ? __int_as_float(nx) : x;
  y = t ? __int_as_float(ny) : y;
  z = t ? __int_as_float(nz) : z;
}

// ---------------------------------------------------------------------------
// 12-bit Morton (16x16x16 over [-4,4]^3) counting sort. Within-cell order is
// nondeterministic (atomics) but the FPS result is invariant to it (lex keys
// carry original indices; bbox skip is conservative).
// ---------------------------------------------------------------------------
__global__ __launch_bounds__(FT) void bin_kernel(const float* __restrict__ pos,
                                                 float* __restrict__ pos_s,
                                                 int* __restrict__ ids_s) {
  __shared__ int hist[4096];
  __shared__ int part[FT];
  const int tid = threadIdx.x;
#pragma unroll
  for (int i = 0; i < 4; ++i) hist[tid * 4 + i] = 0;
  __syncthreads();

  float qx[PPT], qy[PPT], qz[PPT];
  int cell[PPT];
  {
    const float4* p4 = (const float4*)pos + tid * 6;  // 24 floats = 8 points
    float4 a0 = p4[0], a1 = p4[1], a2 = p4[2], a3 = p4[3], a4 = p4[4], a5 = p4[5];
    qx[0]=a0.x; qy[0]=a0.y; qz[0]=a0.z;
    qx[1]=a0.w; qy[1]=a1.x; qz[1]=a1.y;
    qx[2]=a1.z; qy[2]=a1.w; qz[2]=a2.x;
    qx[3]=a2.y; qy[3]=a2.z; qz[3]=a2.w;
    qx[4]=a3.x; qy[4]=a3.y; qz[4]=a3.z;
    qx[5]=a3.w; qy[5]=a4.x; qz[5]=a4.y;
    qx[6]=a4.z; qy[6]=a4.w; qz[6]=a5.x;
    qx[7]=a5.y; qy[7]=a5.z; qz[7]=a5.w;
  }
#pragma unroll
  for (int j = 0; j < PPT; ++j) {
    int ix = min(max((int)floorf((qx[j] + 4.0f) * 2.0f), 0), 15);
    int iy = min(max((int)floorf((qy[j] + 4.0f) * 2.0f), 0), 15);
    int iz = min(max((int)floorf((qz[j] + 4.0f) * 2.0f), 0), 15);
    int m = 0;
#pragma unroll
    for (int b = 0; b < 4; ++b)
      m |= (((ix >> b) & 1) << (3 * b)) | (((iy >> b) & 1) << (3 * b + 1)) |
           (((iz >> b) & 1) << (3 * b + 2));
    cell[j] = m;
    atomicAdd(&hist[m], 1);
  }
  __syncthreads();
  int h0 = hist[tid * 4], h1 = hist[tid * 4 + 1], h2 = hist[tid * 4 + 2], h3 = hist[tid * 4 + 3];
  int s = h0 + h1 + h2 + h3;
  part[tid] = s;
  __syncthreads();
  for (int off = 1; off < FT; off <<= 1) {
    int u = (tid >= off) ? part[tid - off] : 0;
    __syncthreads();
    part[tid] += u;
    __syncthreads();
  }
  int base = part[tid] - s;  // exclusive
  hist[tid * 4 + 0] = base;
  hist[tid * 4 + 1] = base + h0;
  hist[tid * 4 + 2] = base + h0 + h1;
  hist[tid * 4 + 3] = base + h0 + h1 + h2;
  __syncthreads();
#pragma unroll
  for (int j = 0; j < PPT; ++j) {
    int slot = atomicAdd(&hist[cell[j]], 1);
    pos_s[slot * 3 + 0] = qx[j];
    pos_s[slot * 3 + 1] = qy[j];
    pos_s[slot * 3 + 2] = qz[j];
    ids_s[slot] = tid * PPT + j;
  }
}

// key of owned point j: (origidx<<13) | storageidx — lex tie-break == jnp.argmax
#define KEYOF(j) (((((idp[(j) >> 1] >> (((j) & 1) * 16)) & 0xffff)) << 13) | (tid * PPT + (j)))
#define SELP(va, ka, vb, kb) { bool t_ = ((vb) > (va)) || ((vb) == (va) && (kb) < (ka)); \
                               va = t_ ? (vb) : (va); ka = t_ ? (kb) : (ka); }
#define RESCAN() { \
    float v0 = dd[0], v1 = dd[1], v2 = dd[2], v3 = dd[3]; \
    float v4 = dd[4], v5 = dd[5], v6 = dd[6], v7 = dd[7]; \
    int k0 = KEYOF(0), k1 = KEYOF(1), k2 = KEYOF(2), k3 = KEYOF(3); \
    int k4 = KEYOF(4), k5 = KEYOF(5), k6 = KEYOF(6), k7 = KEYOF(7); \
    SELP(v0, k0, v1, k1) SELP(v2, k2, v3, k3) SELP(v4, k4, v5, k5) SELP(v6, k6, v7, k7) \
    SELP(v0, k0, v2, k2) SELP(v4, k4, v6, k6) SELP(v0, k0, v4, k4) \
    bv = v0; bkey = k0; }

// ---------------------------------------------------------------------------
// FPS: 1024 threads x 8 sorted pts. One barrier/iter (double-buffered slots),
// DPP reduces, cached dd (sqrt only on decrease), conservative bbox skip.
// Bit-exact vs reference (lex tie-breaks on original index everywhere).
// ---------------------------------------------------------------------------
__global__ __launch_bounds__(FT) void fps_kernel(const float* __restrict__ pos,
                                                 const float* __restrict__ pos_s,
                                                 const int* __restrict__ ids_s,
                                                 float* __restrict__ pos_out) {
  __shared__ int sC[2][5][16];   // [parity][field: v,k,x,y,z][wave]
  __shared__ unsigned char flag[FPS_N];
  __shared__ int sc[FT];
  const int tid = threadIdx.x, lane = tid & 63, wave = tid >> 6;

  { int* f4 = (int*)flag; f4[tid * 2] = 0; f4[tid * 2 + 1] = 0; }

  float x[PPT], y[PPT], z[PPT], d2[PPT], dd[PPT];
  int idp[PPT / 2];
  {
    const float4* p4 = (const float4*)pos_s + tid * 6;
    float4 a0 = p4[0], a1 = p4[1], a2 = p4[2], a3 = p4[3], a4 = p4[4], a5 = p4[5];
    x[0]=a0.x; y[0]=a0.y; z[0]=a0.z;
    x[1]=a0.w; y[1]=a1.x; z[1]=a1.y;
    x[2]=a1.z; y[2]=a1.w; z[2]=a2.x;
    x[3]=a2.y; y[3]=a2.z; z[3]=a2.w;
    x[4]=a3.x; y[4]=a3.y; z[4]=a3.z;
    x[5]=a3.w; y[5]=a4.x; z[5]=a4.y;
    x[6]=a4.z; y[6]=a4.w; z[6]=a5.x;
    x[7]=a5.y; y[7]=a5.z; z[7]=a5.w;
    const int4* i4 = (const int4*)ids_s + tid * 2;
    int4 b0 = i4[0], b1 = i4[1];
    idp[0] = (b0.x & 0xffff) | (b0.y << 16);
    idp[1] = (b0.z & 0xffff) | (b0.w << 16);
    idp[2] = (b1.x & 0xffff) | (b1.y << 16);
    idp[3] = (b1.z & 0xffff) | (b1.w << 16);
  }

  const float p0x = pos[0], p0y = pos[1], p0z = pos[2];
#pragma unroll
  for (int j = 0; j < PPT; ++j) {
    float s = eucl2(x[j], y[j], z[j], p0x, p0y, p0z);
    int oid = (idp[j >> 1] >> ((j & 1) * 16)) & 0xffff;
    if (oid == 0) { d2[j] = NEGINF; dd[j] = NEGINF; }
    else          { d2[j] = s;      dd[j] = sqrtf(s); }
  }
  // thread bbox (tight: 8-pt Morton run)
  float bnx = x[0], bny = y[0], bnz = z[0], bxx = x[0], bxy = y[0], bxz = z[0];
#pragma unroll
  for (int j = 1; j < PPT; ++j) {
    bnx = fminf(bnx, x[j]); bny = fminf(bny, y[j]); bnz = fminf(bnz, z[j]);
    bxx = fmaxf(bxx, x[j]); bxy = fmaxf(bxy, y[j]); bxz = fmaxf(bxz, z[j]);
  }
  if (tid == 0) flag[0] = 1;

  float bv; int bkey; bool chb;
  // prologue: candidate + wave reduce -> parity 0 slots
  RESCAN();
  chb = false;
  {
    float rv = bv; int rk = bkey;
    dpp_sel2<0x111>(rv, rk); dpp_sel2<0x112>(rv, rk); dpp_sel2<0x114>(rv, rk);
    dpp_sel2<0x118>(rv, rk); dpp_sel2<0x142>(rv, rk); dpp_sel2<0x143>(rv, rk);
    int wkk = __builtin_amdgcn_readlane(rk, 63);
    if (bkey == wkk) {
      float sx = x[0], sy = y[0], sz = z[0];
#pragma unroll
      for (int j = 0; j < PPT; ++j)
        if (j == (bkey & 7)) { sx = x[j]; sy = y[j]; sz = z[j]; }
      sC[0][0][wave] = __float_as_int(bv);
      sC[0][1][wave] = bkey;
      sC[0][2][wave] = __float_as_int(sx);
      sC[0][3][wave] = __float_as_int(sy);
      sC[0][4][wave] = __float_as_int(sz);
    }
  }
  __syncthreads();

  for (int k = 0; k < FPS_K - 1; ++k) {
    const int p = k & 1, pn = p ^ 1;
    // global winner: 16 slots, 4 DPP levels, every lane redundantly
    float gv = __int_as_float(sC[p][0][lane & 15]);
    int   gk = sC[p][1][lane & 15];
    float gx = __int_as_float(sC[p][2][lane & 15]);
    float gy = __int_as_float(sC[p][3][lane & 15]);
    float gz = __int_as_float(sC[p][4][lane & 15]);
    dpp_sel5<0xB1>(gv, gk, gx, gy, gz);    // quad_perm [1,0,3,2]
    dpp_sel5<0x4E>(gv, gk, gx, gy, gz);    // quad_perm [2,3,0,1]
    dpp_sel5<0x124>(gv, gk, gx, gy, gz);   // row_ror:4
    dpp_sel5<0x128>(gv, gk, gx, gy, gz);   // row_ror:8

    const int stor = gk & 8191;
    if ((stor >> 3) == tid) {  // owner marks selected
      const int jj = stor & 7;
#pragma unroll
      for (int j = 0; j < PPT; ++j)
        if (j == jj) { d2[j] = NEGINF; dd[j] = NEGINF; }
      chb = true;
    }
    if (tid == 0) flag[gk >> 13] = 1;

    // conservative bbox-gated update
    float cx = fminf(fmaxf(gx, bnx), bxx);
    float cy = fminf(fmaxf(gy, bny), bxy);
    float cz = fminf(fmaxf(gz, bnz), bxz);
    float ddx = gx - cx, ddy = gy - cy, ddz = gz - cz;
    float bd2 = ddx * ddx + ddy * ddy + ddz * ddz;
    float tub = (bv == NEGINF) ? NEGINF : bv * bv;
    if (bd2 * 0.999f < tub) {
      unsigned cm = 0;
#pragma unroll
      for (int j = 0; j < PPT; ++j) {
        float s = eucl2(x[j], y[j], z[j], gx, gy, gz);
        if (s < d2[j]) { d2[j] = s; cm |= (1u << j); }
      }
      if (cm) {
#pragma unroll
        for (int j = 0; j < PPT; ++j)
          if ((cm >> j) & 1) dd[j] = sqrtf(d2[j]);
        if ((cm >> (bkey & 7)) & 1) chb = true;
      }
    }

    unsigned long long any = __ballot(chb ? 1 : 0);
    if (any) {
      if (chb) { RESCAN(); chb = false; }
      float rv = bv; int rk = bkey;
      dpp_sel2<0x111>(rv, rk); dpp_sel2<0x112>(rv, rk); dpp_sel2<0x114>(rv, rk);
      dpp_sel2<0x118>(rv, rk); dpp_sel2<0x142>(rv, rk); dpp_sel2<0x143>(rv, rk);
      int wkk = __builtin_amdgcn_readlane(rk, 63);
      if (bkey == wkk) {  // unique owner lane publishes wave candidate + coords
        float sx = x[0], sy = y[0], sz = z[0];
#pragma unroll
        for (int j = 0; j < PPT; ++j)
          if (j == (bkey & 7)) { sx = x[j]; sy = y[j]; sz = z[j]; }
        sC[pn][0][wave] = __float_as_int(bv);
        sC[pn][1][wave] = bkey;
        sC[pn][2][wave] = __float_as_int(sx);
        sC[pn][3][wave] = __float_as_int(sy);
        sC[pn][4][wave] = __float_as_int(sz);
      }
    } else {
      if (lane < 5) sC[pn][lane][wave] = sC[p][lane][wave];  // carry forward
    }
    __syncthreads();
  }

  // ---- emit selected points in ascending ORIGINAL index order ----
  const int* fI = (const int*)flag;
  int w0 = fI[tid * 2], w1 = fI[tid * 2 + 1];
  int cnt = __popc(w0) + __popc(w1);
  sc[tid] = cnt;
  __syncthreads();
  for (int off = 1; off < FT; off <<= 1) {
    int u = (tid >= off) ? sc[tid - off] : 0;
    __syncthreads();
    sc[tid] += u;
    __syncthreads();
  }
  int r = sc[tid] - cnt;
#pragma unroll
  for (int j = 0; j < PPT; ++j) {
    int w = (j < 4) ? w0 : w1;
    if ((w >> ((j & 3) * 8)) & 1) {
      int oi = tid * PPT + j;
      pos_out[r * 3 + 0] = pos[oi * 3 + 0];
      pos_out[r * 3 + 1] = pos[oi * 3 + 1];
      pos_out[r * 3 + 2] = pos[oi * 3 + 2];
      ++r;
    }
  }
}

// ---------------------------------------------------------------------------
// W^T (256x256) into scratch (start of mask region; overwritten later).
// ---------------------------------------------------------------------------
__global__ __launch_bounds__(256) void wt_kernel(const float* __restrict__ W,
                                                 float* __restrict__ WT) {
  int i = blockIdx.x * 256 + threadIdx.x;
  int c = i >> 8, cp = i & 255;
  WT[i] = W[cp * 256 + c];
}

// ---------------------------------------------------------------------------
// Fused sparse aggregation + Linear. One block per node m.
// ---------------------------------------------------------------------------
__global__ __launch_bounds__(256) void agg_linear_kernel(
    const float* __restrict__ h, const float* __restrict__ pos,
    const float* __restrict__ nodepos, const float* __restrict__ WT,
    const float* __restrict__ bias, float* __restrict__ embed, float sb) {
  const int m = blockIdx.x;
  const int tid = threadIdx.x;
  const int lane = tid & 63, wave = tid >> 6;
  const float nx = nodepos[m * 3 + 0];
  const float ny = nodepos[m * 3 + 1];
  const float nz = nodepos[m * 3 + 2];
  const float4* h4 = (const float4*)h;

  float4 acc = make_float4(0.f, 0.f, 0.f, 0.f);
  const int base0 = wave * (FPS_N / 4);
  for (int base = base0; base < base0 + (FPS_N / 4); base += 64) {
    int n = base + lane;
    float px = pos[n * 3 + 0], py = pos[n * 3 + 1], pz = pos[n * 3 + 2];
    unsigned long long mb = __ballot((p3sum(px, py, pz, nx, ny, nz) <= sb) ? 1 : 0);
    while (mb) {
      int b = __ffsll(mb) - 1;
      mb &= (mb - 1);
      float4 hv = h4[(size_t)(base + b) * 64 + lane];
      acc.x += hv.x; acc.y += hv.y; acc.z += hv.z; acc.w += hv.w;
    }
  }

  __shared__ float lacc[4][256];
  lacc[wave][lane * 4 + 0] = acc.x;
  lacc[wave][lane * 4 + 1] = acc.y;
  lacc[wave][lane * 4 + 2] = acc.z;
  lacc[wave][lane * 4 + 3] = acc.w;
  __syncthreads();
  __shared__ float aggrow[256];
  float aggv = ((lacc[0][tid] + lacc[1][tid]) + lacc[2][tid]) + lacc[3][tid];
  aggrow[tid] = aggv;
  __syncthreads();

  float o = bias[tid];
#pragma unroll 8
  for (int c = 0; c < 256; ++c)
    o = fmaf(aggrow[c], WT[c * 256 + tid], o);
  embed[(size_t)m * 256 + tid] = o;
}

// ---------------------------------------------------------------------------
// Mask output: mask[n][m] = (sum|d|^3 <= sb) ? 1.0 : 0.0   (8192 x 4096 f32)
// ---------------------------------------------------------------------------
__global__ __launch_bounds__(256) void mask_kernel(const float* __restrict__ pos,
                                                   const float* __restrict__ nodepos,
                                                   float* __restrict__ maskout,
                                                   float sb) {
  int n  = blockIdx.y;
  int m0 = (blockIdx.x * 256 + threadIdx.x) * 4;
  float x = pos[n * 3 + 0], y = pos[n * 3 + 1], z = pos[n * 3 + 2];
  const float4* np4 = (const float4*)(nodepos + (size_t)m0 * 3);
  float4 a = np4[0], bq = np4[1], cq = np4[2];
  float4 r;
  r.x = (p3sum(x, y, z, a.x,  a.y,  a.z)  <= sb) ? 1.0f : 0.0f;
  r.y = (p3sum(x, y, z, a.w,  bq.x, bq.y) <= sb) ? 1.0f : 0.0f;
  r.z = (p3sum(x, y, z, bq.z, bq.w, cq.x) <= sb) ? 1.0f : 0.0f;
  r.w = (p3sum(x, y, z, cq.y, cq.z, cq.w) <= sb) ? 1.0f : 0.0f;
  *(float4*)(maskout + (size_t)n * FPS_K + m0) = r;
}

extern "C" void kernel_launch(void* const* d_in, const int* in_sizes, int n_in,
                              void* d_out, int out_size, void* d_ws, size_t ws_size,
                              hipStream_t stream) {
  (void)in_sizes; (void)n_in; (void)out_size; (void)d_ws; (void)ws_size;
  const float* h   = (const float*)d_in[0];
  const float* pos = (const float*)d_in[1];
  const float* W   = (const float*)d_in[2];
  const float* b   = (const float*)d_in[3];

  float* out     = (float*)d_out;
  float* embed   = out;                                   // 4096*256
  float* pos_out = out + (size_t)FPS_K * CS;              // 4096*3
  float* mask    = pos_out + (size_t)FPS_K * 3;           // 8192*4096
  float* WT      = mask;                                  // scratch (overwritten)
  float* pos_s   = mask + (1 << 21);                      // sorted coords scratch
  int*   ids_s   = (int*)(pos_s + 3 * FPS_N);             // sorted->orig idx

  // Threshold model: ref mask true  <=>  cbrt_f32(s) < 0.3f
  const float  t    = 0.3f;
  const float  ulpv = nextafterf(t, 1.0f) - t;
  const double rmid = (double)t - (double)ulpv * 0.5;
  const double C    = rmid * rmid * rmid;
  float sb = (float)C;
  if (!((double)sb < C)) sb = nextafterf(sb, 0.0f);

  hipLaunchKernelGGL(bin_kernel, dim3(1), dim3(FT), 0, stream, pos, pos_s, ids_s);
  hipLaunchKernelGGL(fps_kernel, dim3(1), dim3(FT), 0, stream, pos, pos_s, ids_s, pos_out);
  hipLaunchKernelGGL(wt_kernel, dim3(256), dim3(256), 0, stream, W, WT);
  hipLaunchKernelGGL(agg_linear_kernel, dim3(FPS_K), dim3(256), 0, stream,
                     h, pos, pos_out, WT, b, embed, sb);
  hipLaunchKernelGGL(mask_kernel, dim3(4, FPS_N), dim3(256), 0, stream,
                     pos, pos_out, mask, sb);
}